// Round 15
// baseline (93.511 us; speedup 1.0000x reference)
//
#include <hip/hip_runtime.h>
#include <math.h>

#define KC 3
#define S 12
#define SS 1728
#define AB 32
#define TLEN 64
#define NTHREADS 896
#define NWAVES 14
#define NACT 864            // 432 slices x 2 threads
#define LN2F 0.69314718055994530942f

typedef float f32x2 __attribute__((ext_vector_type(2)));

__global__ __launch_bounds__(NTHREADS, 2)
void hmm_fwd_kernel(const int* __restrict__ ys,
                    const float* __restrict__ transition,  // [3][12][12]
                    const float* __restrict__ emission,    // [3][12][32]
                    const float* __restrict__ choice,      // [3]
                    const float* __restrict__ prior,       // [3][12]
                    float* __restrict__ out)
{
    // A planes in natural state order n = s0*144 + s1*12 + s2
    __shared__ __align__(16) float APL[KC][SS];
    __shared__ __align__(16) float BETA[SS];
    __shared__ __align__(16) float ECt[KC][AB][16];  // [k][y][slot], slot=(j/6)*8+j%6
    __shared__ __align__(16) float T_s[KC][S][16];   // [k][i][slot]
    __shared__ float p_lin[KC][S];
    __shared__ float c_lin[KC];
    __shared__ int   ys_s[TLEN];
    __shared__ float wsum[NWAVES];

    const int tid = threadIdx.x;

    // ---------------- setup: linear-space tables ----------------
    if (tid < TLEN) ys_s[tid] = ys[tid];

    if (tid == 0) {
        float m = fmaxf(fmaxf(choice[0], choice[1]), choice[2]);
        float e0 = __expf(choice[0]-m), e1 = __expf(choice[1]-m), e2 = __expf(choice[2]-m);
        float inv = 1.f / (e0+e1+e2);
        c_lin[0] = e0*inv; c_lin[1] = e1*inv; c_lin[2] = e2*inv;
    }
    if (tid >= 1 && tid < 1 + KC) {
        int k = tid - 1;
        float m = -INFINITY;
        #pragma unroll
        for (int i = 0; i < S; ++i) m = fmaxf(m, prior[k*S + i]);
        float ev[S]; float s = 0.f;
        #pragma unroll
        for (int i = 0; i < S; ++i) { ev[i] = __expf(prior[k*S + i] - m); s += ev[i]; }
        float inv = 1.f / s;
        #pragma unroll
        for (int i = 0; i < S; ++i) p_lin[k][i] = ev[i] * inv;
    }
    if (tid >= 64 && tid < 64 + KC*S) {      // transition -> softmax probs, padded rows
        int r = tid - 64;
        int k = r / S, i = r % S;
        const float* row = transition + (k*S + i)*S;
        float m = -INFINITY;
        #pragma unroll
        for (int j = 0; j < S; ++j) m = fmaxf(m, row[j]);
        float ev[S]; float s = 0.f;
        #pragma unroll
        for (int j = 0; j < S; ++j) { ev[j] = __expf(row[j] - m); s += ev[j]; }
        float inv = 1.f / s;
        #pragma unroll
        for (int j = 0; j < S; ++j) T_s[k][i][(j/6)*8 + (j%6)] = ev[j] * inv;
    }
    if (tid >= 128 && tid < 128 + KC*S) {    // emission -> ECt = C[k]*softmax, padded
        int r = tid - 128;
        int k = r / S, sj = r % S;
        float cm = fmaxf(fmaxf(choice[0], choice[1]), choice[2]);
        float ce = __expf(choice[k]-cm) /
                   (__expf(choice[0]-cm) + __expf(choice[1]-cm) + __expf(choice[2]-cm));
        const float* row = emission + (k*S + sj)*AB;
        float m = -INFINITY;
        #pragma unroll
        for (int a = 0; a < AB; ++a) m = fmaxf(m, row[a]);
        float ev[AB]; float s = 0.f;
        #pragma unroll
        for (int a = 0; a < AB; ++a) { ev[a] = __expf(row[a] - m); s += ev[a]; }
        float inv = ce / s;
        const int slot = (sj / 6) * 8 + (sj % 6);
        #pragma unroll
        for (int a = 0; a < AB; ++a) ECt[k][a][slot] = ev[a] * inv;
    }
    __syncthreads();

    // ---------------- per-thread statics ----------------
    const bool act = tid < NACT;
    const int ct = act ? tid : (NACT - 1);
    const int sl = ct >> 1;            // slice 0..431
    const int h  = ct & 1;             // output half: columns 6h..6h+5
    const int sk = sl / 144;           // chain
    const int q  = sl % 144;
    const int qh = q / 12, ql = q % 12;

    const int rdb  = (sk == 0) ? q : (sk == 1) ? 144*qh + ql : 12*q;
    const int wstr = (sk == 0) ? 144 : (sk == 1) ? 12 : 1;
    const int wbas = rdb + wstr * 6 * h;
    float* const wap = &APL[sk][wbas];
    const float* const ecp = &ECt[sk][0][8*h];
    const float* const tbp = &T_s[sk][0][8*h];

    // init A planes: thread owns natural states 2p, 2p+1
    if (act) {
        const int sA = 2*tid;
        const int a0 = sA/144, b0 = (sA/12)%12, c0 = sA%12;
        const float pp = p_lin[0][a0]*p_lin[1][b0];
        const float pA = pp*p_lin[2][c0], pB = pp*p_lin[2][c0+1];
        #pragma unroll
        for (int k = 0; k < KC; ++k) {
            float2 v; v.x = pA*c_lin[k]; v.y = pB*c_lin[k];
            *reinterpret_cast<float2*>(&APL[k][sA]) = v;
        }
    }
    __syncthreads();

    // ---------------- 64 steps, 2 barriers each ----------------
    float logR = 0.f, invR = 1.f;
    const int s2p = 2*tid;

    #pragma unroll 1
    for (int t = 0; t < TLEN; ++t) {
        const int y = ys_s[t];
        float4 e03; float2 e45;

        if (act) {
            // E prefetch: depends only on t, completes under barrier-A slack
            e03 = *reinterpret_cast<const float4*>(&ecp[y*16]);
            e45 = *reinterpret_cast<const float2*>(&ecp[y*16 + 4]);

            // phase 1: beta for 2 states (b64 reads/write, conflict-free)
            float2 a0 = *reinterpret_cast<const float2*>(&APL[0][s2p]);
            float2 a1 = *reinterpret_cast<const float2*>(&APL[1][s2p]);
            float2 a2 = *reinterpret_cast<const float2*>(&APL[2][s2p]);
            float2 b;
            b.x = (a0.x + a1.x + a2.x) * invR;
            b.y = (a0.y + a1.y + a2.y) * invR;
            *reinterpret_cast<float2*>(&BETA[s2p]) = b;
        }
        __syncthreads();   // barrier A: BETA ready

        float o0=0.f, o1=0.f, o2=0.f, o3=0.f, o4=0.f, o5=0.f;
        if (act) {
            // gather 12 betas (pair lanes broadcast the same addresses)
            float bv[S];
            if (sk == 0) {
                #pragma unroll
                for (int i = 0; i < S; ++i) bv[i] = BETA[rdb + 144*i];
            } else if (sk == 1) {
                #pragma unroll
                for (int i = 0; i < S; ++i) bv[i] = BETA[rdb + 12*i];
            } else {
                float4 r0 = *reinterpret_cast<const float4*>(&BETA[rdb + 0]);
                float4 r1 = *reinterpret_cast<const float4*>(&BETA[rdb + 4]);
                float4 r2 = *reinterpret_cast<const float4*>(&BETA[rdb + 8]);
                bv[0]=r0.x; bv[1]=r0.y; bv[2] =r0.z; bv[3] =r0.w;
                bv[4]=r1.x; bv[5]=r1.y; bv[6] =r1.z; bv[7] =r1.w;
                bv[8]=r2.x; bv[9]=r2.y; bv[10]=r2.z; bv[11]=r2.w;
            }

            // 12 T rows (broadcast) x 3 packed FMA each (v_pk_fma_f32)
            f32x2 ac0 = {0.f, 0.f}, ac1 = {0.f, 0.f}, ac2 = {0.f, 0.f};
            #pragma unroll
            for (int i = 0; i < S; ++i) {
                float4 t03 = *reinterpret_cast<const float4*>(&tbp[16*i]);
                float2 t45 = *reinterpret_cast<const float2*>(&tbp[16*i + 4]);
                const f32x2 bb = {bv[i], bv[i]};
                ac0 = __builtin_elementwise_fma(bb, (f32x2){t03.x, t03.y}, ac0);
                ac1 = __builtin_elementwise_fma(bb, (f32x2){t03.z, t03.w}, ac1);
                ac2 = __builtin_elementwise_fma(bb, (f32x2){t45.x, t45.y}, ac2);
            }
            ac0 *= (f32x2){e03.x, e03.y};
            ac1 *= (f32x2){e03.z, e03.w};
            ac2 *= (f32x2){e45.x, e45.y};
            o0 = ac0.x; o1 = ac0.y; o2 = ac1.x; o3 = ac1.y; o4 = ac2.x; o5 = ac2.y;

            // write 6 outputs to own plane
            if (sk == 2) {
                if (h == 0) {
                    *reinterpret_cast<float4*>(&wap[0]) = make_float4(o0, o1, o2, o3);
                    *reinterpret_cast<float2*>(&wap[4]) = make_float2(o4, o5);
                } else {
                    *reinterpret_cast<float2*>(&wap[0]) = make_float2(o0, o1);
                    *reinterpret_cast<float4*>(&wap[2]) = make_float4(o2, o3, o4, o5);
                }
            } else {
                wap[0*wstr] = o0; wap[1*wstr] = o1; wap[2*wstr] = o2;
                wap[3*wstr] = o3; wap[4*wstr] = o4; wap[5*wstr] = o5;
            }
        }

        if ((t & 7) == 7) {
            float part = o0 + o1 + o2 + o3 + o4 + o5;   // 0 for inactive
            part += __shfl_xor(part, 32); part += __shfl_xor(part, 16);
            part += __shfl_xor(part, 8);  part += __shfl_xor(part, 4);
            part += __shfl_xor(part, 2);  part += __shfl_xor(part, 1);
            if ((tid & 63) == 0) wsum[tid >> 6] = part;
        }
        __syncthreads();   // barrier B: A planes (and wsum) visible

        if ((t & 7) == 7 && t < TLEN-1) {
            float R = 0.f;
            #pragma unroll
            for (int w = 0; w < NWAVES; ++w) R += wsum[w];
            invR = __builtin_amdgcn_rcpf(R);
            logR += __log2f(R);
        } else {
            invR = 1.f;
        }
    }

    // final: total mass at t=63 is in wsum (its normalizer never applied)
    if (tid == 0) {
        float R = 0.f;
        #pragma unroll
        for (int w = 0; w < NWAVES; ++w) R += wsum[w];
        out[0] = LN2F * (__log2f(R) + logR);
    }
}

extern "C" void kernel_launch(void* const* d_in, const int* in_sizes, int n_in,
                              void* d_out, int out_size, void* d_ws, size_t ws_size,
                              hipStream_t stream) {
    const int*   ys         = (const int*)  d_in[0];
    const float* transition = (const float*)d_in[1];
    const float* emission   = (const float*)d_in[2];
    const float* choice     = (const float*)d_in[3];
    const float* prior      = (const float*)d_in[4];
    float* out = (float*)d_out;

    hipLaunchKernelGGL(hmm_fwd_kernel, dim3(1), dim3(NTHREADS), 0, stream,
                       ys, transition, emission, choice, prior, out);
}

// Round 16
// 59.803 us; speedup vs baseline: 1.5637x; 1.5637x over previous
//
#include <hip/hip_runtime.h>
#include <math.h>

#define KC 3
#define S 12
#define SS 1728
#define AB 32
#define TLEN 64
#define NTHREADS 896
#define NWAVES 14
#define NACT 864            // 432 slices x 2 threads
#define LN2F 0.69314718055994530942f

__global__ __launch_bounds__(NTHREADS, 4)   // 4 waves/SIMD -> 128 VGPR cap (round-9 config)
void hmm_fwd_kernel(const int* __restrict__ ys,
                    const float* __restrict__ transition,  // [3][12][12]
                    const float* __restrict__ emission,    // [3][12][32]
                    const float* __restrict__ choice,      // [3]
                    const float* __restrict__ prior,       // [3][12]
                    float* __restrict__ out)
{
    // A planes in natural state order n = s0*144 + s1*12 + s2
    __shared__ __align__(16) float APL[KC][SS];
    __shared__ __align__(16) float BETA[SS];
    __shared__ __align__(16) float ECt[KC][AB][16];  // [k][y][8h+m], padded rows
    __shared__ float T_s[KC][S][S];
    __shared__ float p_lin[KC][S];
    __shared__ float c_lin[KC];
    __shared__ int   ys_s[TLEN];
    __shared__ float wsum[NWAVES];

    const int tid = threadIdx.x;

    // ---------------- setup: linear-space tables ----------------
    if (tid < TLEN) ys_s[tid] = ys[tid];

    if (tid == 0) {
        float m = fmaxf(fmaxf(choice[0], choice[1]), choice[2]);
        float e0 = __expf(choice[0]-m), e1 = __expf(choice[1]-m), e2 = __expf(choice[2]-m);
        float inv = 1.f / (e0+e1+e2);
        c_lin[0] = e0*inv; c_lin[1] = e1*inv; c_lin[2] = e2*inv;
    }
    if (tid >= 1 && tid < 1 + KC) {
        int k = tid - 1;
        float m = -INFINITY;
        #pragma unroll
        for (int i = 0; i < S; ++i) m = fmaxf(m, prior[k*S + i]);
        float ev[S]; float s = 0.f;
        #pragma unroll
        for (int i = 0; i < S; ++i) { ev[i] = __expf(prior[k*S + i] - m); s += ev[i]; }
        float inv = 1.f / s;
        #pragma unroll
        for (int i = 0; i < S; ++i) p_lin[k][i] = ev[i] * inv;
    }
    if (tid >= 64 && tid < 64 + KC*S) {
        int r = tid - 64;
        int k = r / S, i = r % S;
        const float* row = transition + (k*S + i)*S;
        float m = -INFINITY;
        #pragma unroll
        for (int j = 0; j < S; ++j) m = fmaxf(m, row[j]);
        float ev[S]; float s = 0.f;
        #pragma unroll
        for (int j = 0; j < S; ++j) { ev[j] = __expf(row[j] - m); s += ev[j]; }
        float inv = 1.f / s;
        #pragma unroll
        for (int j = 0; j < S; ++j) T_s[k][i][j] = ev[j] * inv;
    }
    if (tid >= 128 && tid < 128 + KC*S) {    // emission -> ECt[k][y][8h+m] = C[k]*softmax
        int r = tid - 128;
        int k = r / S, sj = r % S;
        float cm = fmaxf(fmaxf(choice[0], choice[1]), choice[2]);
        float ce = __expf(choice[k]-cm) /
                   (__expf(choice[0]-cm) + __expf(choice[1]-cm) + __expf(choice[2]-cm));
        const float* row = emission + (k*S + sj)*AB;
        float m = -INFINITY;
        #pragma unroll
        for (int a = 0; a < AB; ++a) m = fmaxf(m, row[a]);
        float ev[AB]; float s = 0.f;
        #pragma unroll
        for (int a = 0; a < AB; ++a) { ev[a] = __expf(row[a] - m); s += ev[a]; }
        float inv = ce / s;
        const int slot = (sj / 6) * 8 + (sj % 6);
        #pragma unroll
        for (int a = 0; a < AB; ++a) ECt[k][a][slot] = ev[a] * inv;
    }
    __syncthreads();

    // ---------------- per-thread statics ----------------
    const bool act = tid < NACT;
    const int ct = act ? tid : (NACT - 1);
    const int sl = ct >> 1;            // slice 0..431
    const int h  = ct & 1;             // output half: columns 6h..6h+5
    const int sk = sl / 144;           // chain
    const int q  = sl % 144;
    const int qh = q / 12, ql = q % 12;

    // beta gather base (natural order), per chain
    const int rdb = (sk == 0) ? q : (sk == 1) ? 144*qh + ql : 12*q;
    // A write base/stride for own chain
    const int wstr = (sk == 0) ? 144 : (sk == 1) ? 12 : 1;
    const int wbas = rdb + wstr * 6 * h;           // j = 6h + m
    float* const wap = &APL[sk][wbas];
    const float* const ecp = &ECt[sk][0][8*h];

    // T columns 6h..6h+5 (compiler will stage from LDS as broadcast reads)
    float Trg[S][6];
    {
        #pragma unroll
        for (int i = 0; i < S; ++i) {
            #pragma unroll
            for (int m = 0; m < 6; ++m) Trg[i][m] = T_s[sk][i][6*h + m];
        }
    }

    // init A planes: thread p owns natural states 2p, 2p+1 (s2 even, no carry)
    if (act) {
        const int sA = 2*tid;
        const int a0 = sA/144, b0 = (sA/12)%12, c0 = sA%12;
        const float pp = p_lin[0][a0]*p_lin[1][b0];
        const float pA = pp*p_lin[2][c0], pB = pp*p_lin[2][c0+1];
        #pragma unroll
        for (int k = 0; k < KC; ++k) {
            float2 v; v.x = pA*c_lin[k]; v.y = pB*c_lin[k];
            *reinterpret_cast<float2*>(&APL[k][sA]) = v;
        }
    }
    __syncthreads();

    // ---------------- 64 steps, 2 barriers each ----------------
    float logR = 0.f, invR = 1.f;
    const int s2p = 2*tid;
    int y = ys_s[0];

    #pragma unroll 1
    for (int t = 0; t < TLEN; ++t) {
        float4 e03; float2 e45;

        if (act) {
            // E prefetch (depends only on y): latency hides under barrier A
            e03 = *reinterpret_cast<const float4*>(&ecp[y*16]);
            e45 = *reinterpret_cast<const float2*>(&ecp[y*16 + 4]);

            // phase 1: beta for 2 states (b64 reads/write, conflict-free)
            float2 a0 = *reinterpret_cast<const float2*>(&APL[0][s2p]);
            float2 a1 = *reinterpret_cast<const float2*>(&APL[1][s2p]);
            float2 a2 = *reinterpret_cast<const float2*>(&APL[2][s2p]);
            float2 b;
            b.x = (a0.x + a1.x + a2.x) * invR;
            b.y = (a0.y + a1.y + a2.y) * invR;
            *reinterpret_cast<float2*>(&BETA[s2p]) = b;
        }
        __syncthreads();   // barrier A: BETA ready

        float acc0=0.f, acc1=0.f, acc2=0.f, acc3=0.f, acc4=0.f, acc5=0.f;
        if (act) {
            // gather 12 betas (pair lanes broadcast the same addresses)
            float bv[S];
            if (sk == 0) {
                #pragma unroll
                for (int i = 0; i < S; ++i) bv[i] = BETA[rdb + 144*i];
            } else if (sk == 1) {
                #pragma unroll
                for (int i = 0; i < S; ++i) bv[i] = BETA[rdb + 12*i];
            } else {
                float4 r0 = *reinterpret_cast<const float4*>(&BETA[rdb + 0]);
                float4 r1 = *reinterpret_cast<const float4*>(&BETA[rdb + 4]);
                float4 r2 = *reinterpret_cast<const float4*>(&BETA[rdb + 8]);
                bv[0]=r0.x; bv[1]=r0.y; bv[2] =r0.z; bv[3] =r0.w;
                bv[4]=r1.x; bv[5]=r1.y; bv[6] =r1.z; bv[7] =r1.w;
                bv[8]=r2.x; bv[9]=r2.y; bv[10]=r2.z; bv[11]=r2.w;
            }

            #pragma unroll
            for (int i = 0; i < S; ++i) {
                const float bb = bv[i];
                acc0 = __builtin_fmaf(bb, Trg[i][0], acc0);
                acc1 = __builtin_fmaf(bb, Trg[i][1], acc1);
                acc2 = __builtin_fmaf(bb, Trg[i][2], acc2);
                acc3 = __builtin_fmaf(bb, Trg[i][3], acc3);
                acc4 = __builtin_fmaf(bb, Trg[i][4], acc4);
                acc5 = __builtin_fmaf(bb, Trg[i][5], acc5);
            }
            acc0 *= e03.x; acc1 *= e03.y; acc2 *= e03.z;
            acc3 *= e03.w; acc4 *= e45.x; acc5 *= e45.y;

            // write 6 outputs to own plane
            if (sk == 2) {
                if (h == 0) {
                    *reinterpret_cast<float4*>(&wap[0]) = make_float4(acc0, acc1, acc2, acc3);
                    *reinterpret_cast<float2*>(&wap[4]) = make_float2(acc4, acc5);
                } else {
                    *reinterpret_cast<float2*>(&wap[0]) = make_float2(acc0, acc1);
                    *reinterpret_cast<float4*>(&wap[2]) = make_float4(acc2, acc3, acc4, acc5);
                }
            } else {
                wap[0*wstr] = acc0; wap[1*wstr] = acc1; wap[2*wstr] = acc2;
                wap[3*wstr] = acc3; wap[4*wstr] = acc4; wap[5*wstr] = acc5;
            }
        }

        y = ys_s[(t + 1) & (TLEN - 1)];    // prefetch next step's symbol

        if ((t & 7) == 7) {
            float part = acc0 + acc1 + acc2 + acc3 + acc4 + acc5;   // 0 for inactive
            part += __shfl_xor(part, 32); part += __shfl_xor(part, 16);
            part += __shfl_xor(part, 8);  part += __shfl_xor(part, 4);
            part += __shfl_xor(part, 2);  part += __shfl_xor(part, 1);
            if ((tid & 63) == 0) wsum[tid >> 6] = part;
        }
        __syncthreads();   // barrier B: A planes (and wsum) visible

        if ((t & 7) == 7 && t < TLEN-1) {
            float R = 0.f;
            #pragma unroll
            for (int w = 0; w < NWAVES; ++w) R += wsum[w];
            invR = __builtin_amdgcn_rcpf(R);
            logR += __log2f(R);
        } else {
            invR = 1.f;
        }
    }

    // final: total mass at t=63 is in wsum (its normalizer never applied)
    if (tid == 0) {
        float R = 0.f;
        #pragma unroll
        for (int w = 0; w < NWAVES; ++w) R += wsum[w];
        out[0] = LN2F * (__log2f(R) + logR);
    }
}

extern "C" void kernel_launch(void* const* d_in, const int* in_sizes, int n_in,
                              void* d_out, int out_size, void* d_ws, size_t ws_size,
                              hipStream_t stream) {
    const int*   ys         = (const int*)  d_in[0];
    const float* transition = (const float*)d_in[1];
    const float* emission   = (const float*)d_in[2];
    const float* choice     = (const float*)d_in[3];
    const float* prior      = (const float*)d_in[4];
    float* out = (float*)d_out;

    hipLaunchKernelGGL(hmm_fwd_kernel, dim3(1), dim3(NTHREADS), 0, stream,
                       ys, transition, emission, choice, prior, out);
}